// Round 1
// baseline (82.831 us; speedup 1.0000x reference)
//
#include <hip/hip_runtime.h>
#include <stdint.h>

#define NB 8
#define NT 2048
#define NC 1024
#define HD 64

typedef __attribute__((ext_vector_type(8)))  short s16x8;
typedef __attribute__((ext_vector_type(4)))  float f32x4;
typedef __attribute__((ext_vector_type(16))) float f32x16;

__device__ inline ushort f2b(float f) {
    union { float f; uint32_t u; } c; c.f = f;
    uint32_t u = c.u;
    uint32_t r = (u + 0x7fffu + ((u >> 16) & 1u)) >> 16;   // RNE, finite inputs
    return (ushort)r;
}

__device__ inline uint32_t cvt_pk_bf16(float lo, float hi) {
    uint32_t r;
    asm volatile("v_cvt_pk_bf16_f32 %0, %1, %2" : "=v"(r) : "v"(lo), "v"(hi));
    return r;
}

// ---------------------------------------------------------------------------
// Kernel 0: W [1024][192] f32  ->  Wt [192][1024] bf16, q-cols pre-scaled by
// 0.125 * log2(e) so attention logits are already base-2.
// ---------------------------------------------------------------------------
__global__ __launch_bounds__(256) void wprep(const float* __restrict__ W,
                                             ushort* __restrict__ wt) {
    int tid = blockIdx.x * 256 + threadIdx.x;   // 192*1024 total
    int n = tid >> 10;          // 0..191 (output col of qkv)
    int k = tid & 1023;         // 0..1023
    float v = W[k * 192 + n];
    if (n < 64) v *= 0.125f * 1.4426950408889634f;
    wt[n * 1024 + k] = f2b(v);
}

// ---------------------------------------------------------------------------
// Kernel 1: qkv = x @ W.  BM=64 rows/block, full N=192, K-loop 32x32.
// 4 waves: each wave owns all 4 m-frags x 3 n-frags (its 48 cols).
// Outputs: qs [8][2048][64] bf16 (pre-scaled), kk same, vt [8][64][2048] bf16.
// ---------------------------------------------------------------------------
#define ASTR 40   // LDS row stride in elements (80 B) for A tile [64][32]
#define WSTR 40   // LDS row stride for Wt tile [192][32]

__global__ __launch_bounds__(256) void qkv_gemm(const float* __restrict__ x,
                                                const ushort* __restrict__ wt,
                                                ushort* __restrict__ qs,
                                                ushort* __restrict__ kk,
                                                ushort* __restrict__ vt) {
    __shared__ ushort Al[2][64 * ASTR];
    __shared__ ushort Wl[2][192 * WSTR];

    const int tid = threadIdx.x;
    const int wv  = tid >> 6;
    const int ln  = tid & 63;
    const int r16 = ln & 15;
    const int hi4 = ln >> 4;          // 0..3
    const int row0 = blockIdx.x * 64;

    // --- staging geometry ---
    const int arow = tid >> 2;        // 0..63
    const int ac   = tid & 3;         // k-chunk of 8
    const float* xsrc = x + (size_t)(row0 + arow) * NC + ac * 8;

    int wcol[3], wc[3];
    const ushort* wsrc[3];
#pragma unroll
    for (int j = 0; j < 3; ++j) {
        int q = tid + 256 * j;        // chunk id 0..767
        wcol[j] = q >> 2;             // 0..191
        wc[j]   = q & 3;
        wsrc[j] = wt + (size_t)wcol[j] * 1024 + wc[j] * 8;
    }

    f32x4 acc[4][3];
#pragma unroll
    for (int i = 0; i < 4; ++i)
#pragma unroll
        for (int j = 0; j < 3; ++j)
#pragma unroll
            for (int e = 0; e < 4; ++e) acc[i][j][e] = 0.f;

    // --- prologue: stage k-step 0 into buf 0 ---
    {
        float4 xa = *(const float4*)(xsrc);
        float4 xb = *(const float4*)(xsrc + 4);
        uint4 wr0 = *(const uint4*)(wsrc[0]);
        uint4 wr1 = *(const uint4*)(wsrc[1]);
        uint4 wr2 = *(const uint4*)(wsrc[2]);
        union { ushort u[8]; s16x8 v; } pk;
        pk.u[0] = f2b(xa.x); pk.u[1] = f2b(xa.y); pk.u[2] = f2b(xa.z); pk.u[3] = f2b(xa.w);
        pk.u[4] = f2b(xb.x); pk.u[5] = f2b(xb.y); pk.u[6] = f2b(xb.z); pk.u[7] = f2b(xb.w);
        *(s16x8*)(&Al[0][arow * ASTR + ac * 8]) = pk.v;
        *(uint4*)(&Wl[0][wcol[0] * WSTR + wc[0] * 8]) = wr0;
        *(uint4*)(&Wl[0][wcol[1] * WSTR + wc[1] * 8]) = wr1;
        *(uint4*)(&Wl[0][wcol[2] * WSTR + wc[2] * 8]) = wr2;
    }
    __syncthreads();

    int buf = 0;
    for (int t = 0; t < 32; ++t) {
        // issue next-step global loads early (in flight across MFMA)
        float4 nxa, nxb; uint4 nw0, nw1, nw2;
        if (t < 31) {
            int k0 = (t + 1) * 32;
            nxa = *(const float4*)(xsrc + k0);
            nxb = *(const float4*)(xsrc + k0 + 4);
            nw0 = *(const uint4*)(wsrc[0] + k0);
            nw1 = *(const uint4*)(wsrc[1] + k0);
            nw2 = *(const uint4*)(wsrc[2] + k0);
        }

        // compute current buffer
        s16x8 af[4], bfr[3];
#pragma unroll
        for (int mi = 0; mi < 4; ++mi)
            af[mi] = *(const s16x8*)(&Al[buf][(mi * 16 + r16) * ASTR + hi4 * 8]);
#pragma unroll
        for (int ni = 0; ni < 3; ++ni) {
            int col = (wv * 3 + ni) * 16 + r16;
            bfr[ni] = *(const s16x8*)(&Wl[buf][col * WSTR + hi4 * 8]);
        }
#pragma unroll
        for (int mi = 0; mi < 4; ++mi)
#pragma unroll
            for (int ni = 0; ni < 3; ++ni)
                acc[mi][ni] = __builtin_amdgcn_mfma_f32_16x16x32_bf16(
                    af[mi], bfr[ni], acc[mi][ni], 0, 0, 0);

        if (t < 31) {
            int nb = buf ^ 1;
            union { ushort u[8]; s16x8 v; } pk;
            pk.u[0] = f2b(nxa.x); pk.u[1] = f2b(nxa.y); pk.u[2] = f2b(nxa.z); pk.u[3] = f2b(nxa.w);
            pk.u[4] = f2b(nxb.x); pk.u[5] = f2b(nxb.y); pk.u[6] = f2b(nxb.z); pk.u[7] = f2b(nxb.w);
            *(s16x8*)(&Al[nb][arow * ASTR + ac * 8]) = pk.v;
            *(uint4*)(&Wl[nb][wcol[0] * WSTR + wc[0] * 8]) = nw0;
            *(uint4*)(&Wl[nb][wcol[1] * WSTR + wc[1] * 8]) = nw1;
            *(uint4*)(&Wl[nb][wcol[2] * WSTR + wc[2] * 8]) = nw2;
        }
        __syncthreads();
        buf ^= 1;
    }

    // --- epilogue: scatter to qs / kk / vt(bf16, transposed) ---
    const int b = row0 >> 11;
#pragma unroll
    for (int mi = 0; mi < 4; ++mi) {
#pragma unroll
        for (int ni = 0; ni < 3; ++ni) {
            int nf = wv * 3 + ni;              // absolute 16-col fragment
            int colg = nf * 16 + r16;          // 0..191
            int rbase = row0 + mi * 16 + hi4 * 4;
            f32x4 v = acc[mi][ni];
            if (nf < 4) {
#pragma unroll
                for (int j = 0; j < 4; ++j)
                    qs[(size_t)(rbase + j) * HD + colg] = f2b(v[j]);
            } else if (nf < 8) {
#pragma unroll
                for (int j = 0; j < 4; ++j)
                    kk[(size_t)(rbase + j) * HD + (colg - 64)] = f2b(v[j]);
            } else {
                int d = colg - 128;
                union { ushort4 s; ushort u[4]; } pk;
#pragma unroll
                for (int j = 0; j < 4; ++j) pk.u[j] = f2b(v[j]);
                *(ushort4*)(&vt[((size_t)(b * 64 + d)) * NT + (rbase & (NT - 1))]) = pk.s;
            }
        }
    }
}

// ---------------------------------------------------------------------------
// Kernel 2: causal flash attention, 1 wave per 32 q-rows (swapped QK^T).
// grid = 512 (8 batches x 64 tiles), big tiles launched first.
// ---------------------------------------------------------------------------
__global__ __launch_bounds__(64) void attn(const ushort* __restrict__ qs,
                                           const ushort* __restrict__ kk,
                                           const ushort* __restrict__ vt,
                                           float* __restrict__ out) {
    __shared__ float tl[64 * 33];

    const int bid  = blockIdx.x;
    const int b    = bid & 7;
    const int tile = 63 - (bid >> 3);          // big-first for balance
    const int l    = threadIdx.x;
    const int qcol = l & 31;
    const int hi   = l >> 5;
    const int r0   = tile * 32;

    const ushort* qb = qs + ((size_t)(b * NT + r0)) * HD;
    const ushort* kb = kk + (size_t)b * NT * HD;
    const ushort* vb = vt + (size_t)b * HD * NT;

    s16x8 qf[4];
#pragma unroll
    for (int c = 0; c < 4; ++c)
        qf[c] = *(const s16x8*)(qb + (size_t)qcol * HD + c * 16 + hi * 8);

    f32x16 o0, o1;
#pragma unroll
    for (int i = 0; i < 16; ++i) { o0[i] = 0.f; o1[i] = 0.f; }
    float m = -3.0e30f, lsum = 0.f;

    s16x8 kf[4], vf[4];
#pragma unroll
    for (int c = 0; c < 4; ++c)
        kf[c] = *(const s16x8*)(kb + (size_t)qcol * HD + c * 16 + hi * 8);
#pragma unroll
    for (int dt = 0; dt < 2; ++dt)
#pragma unroll
        for (int kc = 0; kc < 2; ++kc)
            vf[dt * 2 + kc] = *(const s16x8*)(vb + (size_t)(dt * 32 + qcol) * NT
                                              + kc * 16 + hi * 8);

    for (int kt = 0; kt <= tile; ++kt) {
        // S^T = K . Q^T   (col = q, row-regs = k_local)
        f32x16 s;
#pragma unroll
        for (int i = 0; i < 16; ++i) s[i] = 0.f;
#pragma unroll
        for (int c = 0; c < 4; ++c)
            s = __builtin_amdgcn_mfma_f32_32x32x16_bf16(kf[c], qf[c], s, 0, 0, 0);

        // prefetch next K/V tiles
        s16x8 kfn[4], vfn[4];
        if (kt < tile) {
            const ushort* kr = kb + (size_t)((kt + 1) * 32 + qcol) * HD;
#pragma unroll
            for (int c = 0; c < 4; ++c)
                kfn[c] = *(const s16x8*)(kr + c * 16 + hi * 8);
#pragma unroll
            for (int dt = 0; dt < 2; ++dt)
#pragma unroll
                for (int kc = 0; kc < 2; ++kc)
                    vfn[dt * 2 + kc] = *(const s16x8*)(vb + (size_t)(dt * 32 + qcol) * NT
                                                       + (kt + 1) * 32 + kc * 16 + hi * 8);
        }

        // online softmax (per-lane scalar state: one q per lane)
        const bool diag = (kt == tile);
        float p[16];
#pragma unroll
        for (int r = 0; r < 16; ++r) {
            int klocal = (r & 3) + 8 * (r >> 2) + 4 * hi;
            float sv = s[r];
            if (diag && klocal > qcol) sv = -3.0e30f;
            p[r] = sv;
        }
        float pmax = p[0];
#pragma unroll
        for (int r = 1; r < 16; ++r) pmax = fmaxf(pmax, p[r]);
        pmax = fmaxf(pmax, __shfl_xor(pmax, 32));
        float mnew = fmaxf(m, pmax);
        float corr = exp2f(m - mnew);
        m = mnew;
        float rs = 0.f;
#pragma unroll
        for (int r = 0; r < 16; ++r) { p[r] = exp2f(p[r] - mnew); rs += p[r]; }
        rs += __shfl_xor(rs, 32);
        lsum = lsum * corr + rs;
#pragma unroll
        for (int i = 0; i < 16; ++i) { o0[i] *= corr; o1[i] *= corr; }

        // P (f32, S^T layout) -> bf16 B-fragments via cvt_pk + lane^32 exchange
#pragma unroll
        for (int kc = 0; kc < 2; ++kc) {
            int pb = kc * 8;
            uint32_t a0 = cvt_pk_bf16(p[pb + 0], p[pb + 1]);
            uint32_t a1 = cvt_pk_bf16(p[pb + 2], p[pb + 3]);
            uint32_t b0 = cvt_pk_bf16(p[pb + 4], p[pb + 5]);
            uint32_t b1 = cvt_pk_bf16(p[pb + 6], p[pb + 7]);
            uint32_t a0x = __shfl_xor(a0, 32);
            uint32_t a1x = __shfl_xor(a1, 32);
            uint32_t b0x = __shfl_xor(b0, 32);
            uint32_t b1x = __shfl_xor(b1, 32);
            union { uint32_t w[4]; s16x8 v; } frag;
            frag.w[0] = hi ? b0x : a0;
            frag.w[1] = hi ? b1x : a1;
            frag.w[2] = hi ? b0  : a0x;
            frag.w[3] = hi ? b1  : a1x;
            o0 = __builtin_amdgcn_mfma_f32_32x32x16_bf16(vf[0 * 2 + kc], frag.v, o0, 0, 0, 0);
            o1 = __builtin_amdgcn_mfma_f32_32x32x16_bf16(vf[1 * 2 + kc], frag.v, o1, 0, 0, 0);
        }

        if (kt < tile) {
#pragma unroll
            for (int c = 0; c < 4; ++c) kf[c] = kfn[c];
#pragma unroll
            for (int c = 0; c < 4; ++c) vf[c] = vfn[c];
        }
    }

    // --- epilogue: normalize, transpose via LDS, coalesced f32 store ---
    float inv = 1.0f / lsum;
#pragma unroll
    for (int r = 0; r < 16; ++r) {
        int d = (r & 3) + 8 * (r >> 2) + 4 * hi;
        tl[d * 33 + qcol]        = o0[r] * inv;
        tl[(32 + d) * 33 + qcol] = o1[r] * inv;
    }
    __syncthreads();
    const int q = l >> 1, half = l & 1;
    float* orow = out + ((size_t)(b * NT + r0 + q)) * HD + half * 32;
#pragma unroll
    for (int i = 0; i < 32; i += 4) {
        float4 v;
        v.x = tl[(half * 32 + i + 0) * 33 + q];
        v.y = tl[(half * 32 + i + 1) * 33 + q];
        v.z = tl[(half * 32 + i + 2) * 33 + q];
        v.w = tl[(half * 32 + i + 3) * 33 + q];
        *(float4*)(orow + i) = v;
    }
}

// ---------------------------------------------------------------------------
extern "C" void kernel_launch(void* const* d_in, const int* in_sizes, int n_in,
                              void* d_out, int out_size, void* d_ws, size_t ws_size,
                              hipStream_t stream) {
    const float* x = (const float*)d_in[0];
    const float* W = (const float*)d_in[1];
    float* out = (float*)d_out;

    ushort* qs = (ushort*)d_ws;                 // [8][2048][64] bf16 (pre-scaled q)
    ushort* kk = qs + (size_t)NB * NT * HD;     // [8][2048][64]
    ushort* vt = kk + (size_t)NB * NT * HD;     // [8][64][2048]  (V transposed)
    ushort* wt = vt + (size_t)NB * NT * HD;     // [192][1024]    (W^T bf16)

    wprep<<<768, 256, 0, stream>>>(W, wt);
    qkv_gemm<<<256, 256, 0, stream>>>(x, wt, qs, kk, vt);
    attn<<<512, 64, 0, stream>>>(qs, kk, vt, out);
}

// Round 2
// 58.336 us; speedup vs baseline: 1.4199x; 1.4199x over previous
//
#include <hip/hip_runtime.h>
#include <stdint.h>

#define NB 8
#define NT 2048
#define NC 1024
#define HD 64

typedef __attribute__((ext_vector_type(8)))  short s16x8;
typedef __attribute__((ext_vector_type(4)))  float f32x4;
typedef __attribute__((ext_vector_type(16))) float f32x16;

__device__ inline ushort f2b(float f) {
    union { float f; uint32_t u; } c; c.f = f;
    uint32_t u = c.u;
    uint32_t r = (u + 0x7fffu + ((u >> 16) & 1u)) >> 16;   // RNE, finite inputs
    return (ushort)r;
}

__device__ inline uint32_t cvt_pk_bf16(float lo, float hi) {
    uint32_t r;
    asm volatile("v_cvt_pk_bf16_f32 %0, %1, %2" : "=v"(r) : "v"(lo), "v"(hi));
    return r;
}

// ---------------------------------------------------------------------------
// Kernel 0: W [1024][192] f32  ->  Wt [192][1024] bf16, q-cols pre-scaled by
// 0.125 * log2(e) so attention logits are already base-2.
// ---------------------------------------------------------------------------
__global__ __launch_bounds__(256) void wprep(const float* __restrict__ W,
                                             ushort* __restrict__ wt) {
    int tid = blockIdx.x * 256 + threadIdx.x;   // 192*1024 total
    int n = tid >> 10;          // 0..191 (output col of qkv)
    int k = tid & 1023;         // 0..1023
    float v = W[k * 192 + n];
    if (n < 64) v *= 0.125f * 1.4426950408889634f;
    wt[n * 1024 + k] = f2b(v);
}

// ---------------------------------------------------------------------------
// Kernel 1: qkv = x @ W.  BM=64 rows/block, full N=192, K-loop 32x32.
// 4 waves: each wave owns all 4 m-frags x 3 n-frags (its 48 cols).
// Outputs: qs [8][2048][64] bf16 (pre-scaled), kk same, vt [8][64][2048] bf16.
// ---------------------------------------------------------------------------
#define ASTR 40   // LDS row stride in elements (80 B) for A tile [64][32]
#define WSTR 40   // LDS row stride for Wt tile [192][32]

__global__ __launch_bounds__(256) void qkv_gemm(const float* __restrict__ x,
                                                const ushort* __restrict__ wt,
                                                ushort* __restrict__ qs,
                                                ushort* __restrict__ kk,
                                                ushort* __restrict__ vt) {
    __shared__ ushort Al[2][64 * ASTR];
    __shared__ ushort Wl[2][192 * WSTR];

    const int tid = threadIdx.x;
    const int wv  = tid >> 6;
    const int ln  = tid & 63;
    const int r16 = ln & 15;
    const int hi4 = ln >> 4;          // 0..3
    const int row0 = blockIdx.x * 64;

    // --- staging geometry ---
    const int arow = tid >> 2;        // 0..63
    const int ac   = tid & 3;         // k-chunk of 8
    const float* xsrc = x + (size_t)(row0 + arow) * NC + ac * 8;

    int wcol[3], wc[3];
    const ushort* wsrc[3];
#pragma unroll
    for (int j = 0; j < 3; ++j) {
        int q = tid + 256 * j;        // chunk id 0..767
        wcol[j] = q >> 2;             // 0..191
        wc[j]   = q & 3;
        wsrc[j] = wt + (size_t)wcol[j] * 1024 + wc[j] * 8;
    }

    f32x4 acc[4][3];
#pragma unroll
    for (int i = 0; i < 4; ++i)
#pragma unroll
        for (int j = 0; j < 3; ++j)
#pragma unroll
            for (int e = 0; e < 4; ++e) acc[i][j][e] = 0.f;

    // --- prologue: stage k-step 0 into buf 0 ---
    {
        float4 xa = *(const float4*)(xsrc);
        float4 xb = *(const float4*)(xsrc + 4);
        uint4 wr0 = *(const uint4*)(wsrc[0]);
        uint4 wr1 = *(const uint4*)(wsrc[1]);
        uint4 wr2 = *(const uint4*)(wsrc[2]);
        union { ushort u[8]; s16x8 v; } pk;
        pk.u[0] = f2b(xa.x); pk.u[1] = f2b(xa.y); pk.u[2] = f2b(xa.z); pk.u[3] = f2b(xa.w);
        pk.u[4] = f2b(xb.x); pk.u[5] = f2b(xb.y); pk.u[6] = f2b(xb.z); pk.u[7] = f2b(xb.w);
        *(s16x8*)(&Al[0][arow * ASTR + ac * 8]) = pk.v;
        *(uint4*)(&Wl[0][wcol[0] * WSTR + wc[0] * 8]) = wr0;
        *(uint4*)(&Wl[0][wcol[1] * WSTR + wc[1] * 8]) = wr1;
        *(uint4*)(&Wl[0][wcol[2] * WSTR + wc[2] * 8]) = wr2;
    }
    __syncthreads();

    int buf = 0;
    for (int t = 0; t < 32; ++t) {
        // issue next-step global loads early (in flight across MFMA)
        float4 nxa, nxb; uint4 nw0, nw1, nw2;
        if (t < 31) {
            int k0 = (t + 1) * 32;
            nxa = *(const float4*)(xsrc + k0);
            nxb = *(const float4*)(xsrc + k0 + 4);
            nw0 = *(const uint4*)(wsrc[0] + k0);
            nw1 = *(const uint4*)(wsrc[1] + k0);
            nw2 = *(const uint4*)(wsrc[2] + k0);
        }

        // compute current buffer
        s16x8 af[4], bfr[3];
#pragma unroll
        for (int mi = 0; mi < 4; ++mi)
            af[mi] = *(const s16x8*)(&Al[buf][(mi * 16 + r16) * ASTR + hi4 * 8]);
#pragma unroll
        for (int ni = 0; ni < 3; ++ni) {
            int col = (wv * 3 + ni) * 16 + r16;
            bfr[ni] = *(const s16x8*)(&Wl[buf][col * WSTR + hi4 * 8]);
        }
#pragma unroll
        for (int mi = 0; mi < 4; ++mi)
#pragma unroll
            for (int ni = 0; ni < 3; ++ni)
                acc[mi][ni] = __builtin_amdgcn_mfma_f32_16x16x32_bf16(
                    af[mi], bfr[ni], acc[mi][ni], 0, 0, 0);

        if (t < 31) {
            int nb = buf ^ 1;
            union { ushort u[8]; s16x8 v; } pk;
            pk.u[0] = f2b(nxa.x); pk.u[1] = f2b(nxa.y); pk.u[2] = f2b(nxa.z); pk.u[3] = f2b(nxa.w);
            pk.u[4] = f2b(nxb.x); pk.u[5] = f2b(nxb.y); pk.u[6] = f2b(nxb.z); pk.u[7] = f2b(nxb.w);
            *(s16x8*)(&Al[nb][arow * ASTR + ac * 8]) = pk.v;
            *(uint4*)(&Wl[nb][wcol[0] * WSTR + wc[0] * 8]) = nw0;
            *(uint4*)(&Wl[nb][wcol[1] * WSTR + wc[1] * 8]) = nw1;
            *(uint4*)(&Wl[nb][wcol[2] * WSTR + wc[2] * 8]) = nw2;
        }
        __syncthreads();
        buf ^= 1;
    }

    // --- epilogue: scatter to qs / kk / vt(bf16, transposed) ---
    const int b = row0 >> 11;
#pragma unroll
    for (int mi = 0; mi < 4; ++mi) {
#pragma unroll
        for (int ni = 0; ni < 3; ++ni) {
            int nf = wv * 3 + ni;              // absolute 16-col fragment
            int colg = nf * 16 + r16;          // 0..191
            int rbase = row0 + mi * 16 + hi4 * 4;
            f32x4 v = acc[mi][ni];
            if (nf < 4) {
#pragma unroll
                for (int j = 0; j < 4; ++j)
                    qs[(size_t)(rbase + j) * HD + colg] = f2b(v[j]);
            } else if (nf < 8) {
#pragma unroll
                for (int j = 0; j < 4; ++j)
                    kk[(size_t)(rbase + j) * HD + (colg - 64)] = f2b(v[j]);
            } else {
                int d = colg - 128;
                union { ushort4 s; ushort u[4]; } pk;
#pragma unroll
                for (int j = 0; j < 4; ++j) pk.u[j] = f2b(v[j]);
                *(ushort4*)(&vt[((size_t)(b * 64 + d)) * NT + (rbase & (NT - 1))]) = pk.s;
            }
        }
    }
}

// ---------------------------------------------------------------------------
// Kernel 2: causal flash attention. 4 waves/block, intra-block split-K:
// wave w handles k-tiles w, w+4, ... of its 32-row q-tile; partial
// (m,l,o) merged in LDS with exp2 rescaling. grid = 512, big tiles first.
// ---------------------------------------------------------------------------
__global__ __launch_bounds__(256) void attn(const ushort* __restrict__ qs,
                                            const ushort* __restrict__ kk,
                                            const ushort* __restrict__ vt,
                                            float* __restrict__ out) {
    __shared__ float ob[4][64][33];   // per-wave unnormalized O^T partials
    __shared__ float ml[4][2][32];    // per-wave m / lsum per q col

    const int bid  = blockIdx.x;
    const int b    = bid & 7;
    const int tile = 63 - (bid >> 3);          // big-first for balance
    const int tid  = threadIdx.x;
    const int wv   = tid >> 6;                 // 0..3  (k-split index)
    const int l    = tid & 63;
    const int qcol = l & 31;
    const int hi   = l >> 5;
    const int r0   = tile * 32;

    const ushort* qb = qs + ((size_t)(b * NT + r0)) * HD;
    const ushort* kb = kk + (size_t)b * NT * HD;
    const ushort* vb = vt + (size_t)b * HD * NT;

    s16x8 qf[4];
#pragma unroll
    for (int c = 0; c < 4; ++c)
        qf[c] = *(const s16x8*)(qb + (size_t)qcol * HD + c * 16 + hi * 8);

    f32x16 o0, o1;
#pragma unroll
    for (int i = 0; i < 16; ++i) { o0[i] = 0.f; o1[i] = 0.f; }
    float m = -3.0e30f, lsum = 0.f;

    if (wv <= tile) {
        s16x8 kf[4], vf[4];
        {
            const ushort* kr = kb + (size_t)(wv * 32 + qcol) * HD;
#pragma unroll
            for (int c = 0; c < 4; ++c)
                kf[c] = *(const s16x8*)(kr + c * 16 + hi * 8);
#pragma unroll
            for (int dt = 0; dt < 2; ++dt)
#pragma unroll
                for (int kc = 0; kc < 2; ++kc)
                    vf[dt * 2 + kc] = *(const s16x8*)(vb + (size_t)(dt * 32 + qcol) * NT
                                                      + wv * 32 + kc * 16 + hi * 8);
        }

        for (int kt = wv; kt <= tile; kt += 4) {
            // S^T = K . Q^T   (col = q, row-regs = k_local)
            f32x16 s;
#pragma unroll
            for (int i = 0; i < 16; ++i) s[i] = 0.f;
#pragma unroll
            for (int c = 0; c < 4; ++c)
                s = __builtin_amdgcn_mfma_f32_32x32x16_bf16(kf[c], qf[c], s, 0, 0, 0);

            // prefetch this wave's next K/V tiles (stride 4)
            s16x8 kfn[4], vfn[4];
            const bool more = (kt + 4 <= tile);
            if (more) {
                const ushort* kr = kb + (size_t)((kt + 4) * 32 + qcol) * HD;
#pragma unroll
                for (int c = 0; c < 4; ++c)
                    kfn[c] = *(const s16x8*)(kr + c * 16 + hi * 8);
#pragma unroll
                for (int dt = 0; dt < 2; ++dt)
#pragma unroll
                    for (int kc = 0; kc < 2; ++kc)
                        vfn[dt * 2 + kc] = *(const s16x8*)(vb + (size_t)(dt * 32 + qcol) * NT
                                                           + (kt + 4) * 32 + kc * 16 + hi * 8);
            }

            // online softmax (per-lane scalar state: one q per lane)
            const bool diag = (kt == tile);
            float p[16];
#pragma unroll
            for (int r = 0; r < 16; ++r) {
                int klocal = (r & 3) + 8 * (r >> 2) + 4 * hi;
                float sv = s[r];
                if (diag && klocal > qcol) sv = -3.0e30f;
                p[r] = sv;
            }
            float pmax = p[0];
#pragma unroll
            for (int r = 1; r < 16; ++r) pmax = fmaxf(pmax, p[r]);
            pmax = fmaxf(pmax, __shfl_xor(pmax, 32));
            float mnew = fmaxf(m, pmax);
            float corr = exp2f(m - mnew);
            m = mnew;
            float rs = 0.f;
#pragma unroll
            for (int r = 0; r < 16; ++r) { p[r] = exp2f(p[r] - mnew); rs += p[r]; }
            rs += __shfl_xor(rs, 32);
            lsum = lsum * corr + rs;
#pragma unroll
            for (int i = 0; i < 16; ++i) { o0[i] *= corr; o1[i] *= corr; }

            // P (f32, S^T layout) -> bf16 B-fragments via cvt_pk + lane^32 exchange
#pragma unroll
            for (int kc = 0; kc < 2; ++kc) {
                int pb = kc * 8;
                uint32_t a0 = cvt_pk_bf16(p[pb + 0], p[pb + 1]);
                uint32_t a1 = cvt_pk_bf16(p[pb + 2], p[pb + 3]);
                uint32_t b0 = cvt_pk_bf16(p[pb + 4], p[pb + 5]);
                uint32_t b1 = cvt_pk_bf16(p[pb + 6], p[pb + 7]);
                uint32_t a0x = __shfl_xor(a0, 32);
                uint32_t a1x = __shfl_xor(a1, 32);
                uint32_t b0x = __shfl_xor(b0, 32);
                uint32_t b1x = __shfl_xor(b1, 32);
                union { uint32_t w[4]; s16x8 v; } frag;
                frag.w[0] = hi ? b0x : a0;
                frag.w[1] = hi ? b1x : a1;
                frag.w[2] = hi ? b0  : a0x;
                frag.w[3] = hi ? b1  : a1x;
                o0 = __builtin_amdgcn_mfma_f32_32x32x16_bf16(vf[0 * 2 + kc], frag.v, o0, 0, 0, 0);
                o1 = __builtin_amdgcn_mfma_f32_32x32x16_bf16(vf[1 * 2 + kc], frag.v, o1, 0, 0, 0);
            }

            if (more) {
#pragma unroll
                for (int c = 0; c < 4; ++c) kf[c] = kfn[c];
#pragma unroll
                for (int c = 0; c < 4; ++c) vf[c] = vfn[c];
            }
        }
    }

    // --- write per-wave partials (unnormalized) ---
#pragma unroll
    for (int r = 0; r < 16; ++r) {
        int d = (r & 3) + 8 * (r >> 2) + 4 * hi;
        ob[wv][d][qcol]      = o0[r];
        ob[wv][d + 32][qcol] = o1[r];
    }
    if (hi == 0) {
        ml[wv][0][qcol] = m;
        ml[wv][1][qcol] = lsum;
    }
    __syncthreads();

    // --- merge 4 partials + coalesced f32 store ---
    // thread -> (q = tid>>3, d block of 8 at (tid&7)*8)
    const int q  = tid >> 3;
    const int j0 = (tid & 7) * 8;
    float mw[4];
#pragma unroll
    for (int w = 0; w < 4; ++w) mw[w] = ml[w][0][q];
    float M = fmaxf(fmaxf(mw[0], mw[1]), fmaxf(mw[2], mw[3]));
    float sw[4]; float L = 0.f;
#pragma unroll
    for (int w = 0; w < 4; ++w) {
        sw[w] = exp2f(mw[w] - M);
        L += sw[w] * ml[w][1][q];
    }
    float invL = 1.0f / L;
    float vals[8];
#pragma unroll
    for (int j = 0; j < 8; ++j) {
        int d = j0 + j;
        float acc = 0.f;
#pragma unroll
        for (int w = 0; w < 4; ++w) acc += sw[w] * ob[w][d][q];
        vals[j] = acc * invL;
    }
    float* orow = out + ((size_t)(b * NT + r0 + q)) * HD + j0;
    *(float4*)(orow)     = make_float4(vals[0], vals[1], vals[2], vals[3]);
    *(float4*)(orow + 4) = make_float4(vals[4], vals[5], vals[6], vals[7]);
}

// ---------------------------------------------------------------------------
extern "C" void kernel_launch(void* const* d_in, const int* in_sizes, int n_in,
                              void* d_out, int out_size, void* d_ws, size_t ws_size,
                              hipStream_t stream) {
    const float* x = (const float*)d_in[0];
    const float* W = (const float*)d_in[1];
    float* out = (float*)d_out;

    ushort* qs = (ushort*)d_ws;                 // [8][2048][64] bf16 (pre-scaled q)
    ushort* kk = qs + (size_t)NB * NT * HD;     // [8][2048][64]
    ushort* vt = kk + (size_t)NB * NT * HD;     // [8][64][2048]  (V transposed)
    ushort* wt = vt + (size_t)NB * NT * HD;     // [192][1024]    (W^T bf16)

    wprep<<<768, 256, 0, stream>>>(W, wt);
    qkv_gemm<<<256, 256, 0, stream>>>(x, wt, qs, kk, vt);
    attn<<<512, 256, 0, stream>>>(qs, kk, vt, out);
}